// Round 8
// baseline (1209.017 us; speedup 1.0000x reference)
//
#include <hip/hip_runtime.h>
#include <cstdint>

typedef __attribute__((ext_vector_type(8))) short bf16x8;
typedef __attribute__((ext_vector_type(4))) float f32x4;

// ---------- helpers ----------
__device__ __forceinline__ float bf2f(unsigned short u) {
    union { unsigned int i; float f; } v; v.i = ((unsigned int)u) << 16; return v.f;
}
__device__ __forceinline__ float bfhi(unsigned int w) {
    union { unsigned int i; float f; } v; v.i = w & 0xffff0000u; return v.f;
}
__device__ __forceinline__ float bflo(unsigned int w) {
    union { unsigned int i; float f; } v; v.i = w << 16; return v.f;
}
__device__ __forceinline__ unsigned short f2bf(float f) {
    union { float ff; unsigned int i; } v; v.ff = f;
    unsigned int r = (v.i + 0x7fffu + ((v.i >> 16) & 1u)) >> 16;
    return (unsigned short)r;
}
// gate-permuted column -> original column (nc in [0,384))
__device__ __forceinline__ int origcol(int nc) {
    int w = nc / 96, rem = nc % 96, g = rem / 32, cc = rem % 32;
    return g * 128 + w * 32 + cc;
}
// async global->LDS, 16B per lane; LDS dest = wave-uniform base + lane*16
__device__ __forceinline__ void gload_lds16(const unsigned short* g, unsigned short* ldsBase) {
    __builtin_amdgcn_global_load_lds(
        (const __attribute__((address_space(1))) unsigned int*)(const void*)g,
        (__attribute__((address_space(3))) unsigned int*)(void*)ldsBase,
        16, 0, 0);
}

// ---------- runtime dtype detection ----------
__global__ void detect_kernel(const unsigned int* __restrict__ x32,
                              const int* __restrict__ ei32,
                              int* __restrict__ flags)
{
    __shared__ int insaneS;
    __shared__ int orS;
    int tid = threadIdx.x;
    if (tid == 0) { insaneS = 0; orS = 0; }
    __syncthreads();
    int insane = 0;
    for (int j = tid; j < 512; j += 256) {
        unsigned int w = x32[j];
        int e = (int)((w >> 7) & 0xFF);
        if (e > 135 || e < 100) insane++;
    }
    int ov = 0;
    for (int j = tid; j < 256; j += 256) ov |= ei32[2 * j + 1];
    atomicAdd(&insaneS, insane);
    atomicOr(&orS, ov);
    __syncthreads();
    if (tid == 0) {
        flags[0] = (insaneS < 64) ? 1 : 0;   // 1 = bf16-packed floats
        flags[1] = (orS == 0) ? 1 : 0;       // 1 = int64 edges
    }
}

// ---------- all-weights conversion (bf16-or-f32 -> f32), one launch ----------
__global__ void convall_kernel(const void* W_in, const void* W_mpnn, const void* W_ih,
                               const void* W_hh, const void* b_ih, const void* b_hh,
                               const void* W_pred, const void* b_pred,
                               float* __restrict__ Winf, float* __restrict__ Wmf,
                               float* __restrict__ Wihf, float* __restrict__ Whhf,
                               float* __restrict__ bihf, float* __restrict__ bhhf,
                               float* __restrict__ Wpf, float* __restrict__ bpf,
                               int steps, const int* __restrict__ flags)
{
    int i = blockIdx.x * 256 + threadIdx.x;
    int bf = flags[0];
    auto get = [&](const void* p, int idx) -> float {
        return bf ? bf2f(((const unsigned short*)p)[idx]) : ((const float*)p)[idx];
    };
    int n0 = 8192, n1 = n0 + steps * 16384, n2 = n1 + 49152, n3 = n2 + 49152;
    int n4 = n3 + 384, n5 = n4 + 384, n6 = n5 + 128, n7 = n6 + 1;
    if      (i < n0) Winf[i]      = get(W_in,   i);
    else if (i < n1) Wmf[i - n0]  = get(W_mpnn, i - n0);
    else if (i < n2) Wihf[i - n1] = get(W_ih,   i - n1);
    else if (i < n3) Whhf[i - n2] = get(W_hh,   i - n2);
    else if (i < n4) bihf[i - n3] = get(b_ih,   i - n3);
    else if (i < n5) bhhf[i - n4] = get(b_hh,   i - n4);
    else if (i < n6) Wpf[i - n5]  = get(W_pred, i - n5);
    else if (i < n7) bpf[i - n6]  = get(b_pred, i - n6);
}

// Wcomb[step][k][j] = sum_t W_mpnn[step][k][t] * W_ih[j][t]   ([steps][128][384])
__global__ void wcomb_kernel(const float* __restrict__ Wm,
                             const float* __restrict__ Wih,
                             float* __restrict__ Wcomb, int steps)
{
    int i = blockIdx.x * 256 + threadIdx.x;
    int total = steps * 49152;
    if (i >= total) return;
    int step = i / 49152;
    int rem = i - step * 49152;
    int k = rem / 384;
    int j = rem - k * 384;
    const float* wm = Wm + ((long)step * 128 + k) * 128;
    const float* wi = Wih + (long)j * 128;
    float s = 0.f;
#pragma unroll 8
    for (int t = 0; t < 128; ++t) s += wm[t] * wi[t];
    Wcomb[i] = s;
}

// ---------- pack weights into MFMA-fragment-ready bf16 layout ----------
__global__ void pack_gates(const float* __restrict__ Wcomb,
                           const float* __restrict__ Whhf,
                           const float* __restrict__ bihf, const float* __restrict__ bhhf,
                           unsigned short* __restrict__ Bci,
                           unsigned short* __restrict__ Bhh,
                           float* __restrict__ bip, float* __restrict__ bhp,
                           int steps)
{
    int i = blockIdx.x * 256 + threadIdx.x;
    int nmat = steps * 49152;
    if (i < nmat) {
        int s = i / 49152, r = i - s * 49152;
        int t = r >> 11, rem = r & 2047;
        int ks = rem >> 9, l = (rem >> 3) & 63, j = rem & 7;
        int k = ks * 32 + (l >> 4) * 8 + j;
        int oc = origcol(t * 16 + (l & 15));
        Bci[i] = f2bf(Wcomb[(long)s * 49152 + k * 384 + oc]);
    } else if (i < nmat + 49152) {
        int r = i - nmat;
        int t = r >> 11, rem = r & 2047;
        int ks = rem >> 9, l = (rem >> 3) & 63, j = rem & 7;
        int k = ks * 32 + (l >> 4) * 8 + j;
        int oc = origcol(t * 16 + (l & 15));
        Bhh[r] = f2bf(Whhf[(long)oc * 128 + k]);
    } else if (i < nmat + 49152 + 768) {
        int b = i - nmat - 49152;
        if (b < 384) bip[b] = bihf[origcol(b)];
        else         bhp[b - 384] = bhhf[origcol(b - 384)];
    }
}

// pack W_in ([128][64] row-major fp32) -> [8 t][2 ks][64][8] bf16
__global__ void pack_in(const float* __restrict__ Winf, unsigned short* __restrict__ Bin)
{
    int r = blockIdx.x * 256 + threadIdx.x;
    if (r >= 8192) return;
    int t = r >> 10, rem = r & 1023;
    int ks = rem >> 9, l = (rem >> 3) & 63, j = rem & 7;
    int k = ks * 32 + (l >> 4) * 8 + j;
    int col = t * 16 + (l & 15);
    Bin[r] = f2bf(Winf[col * 64 + k]);
}

// ---------- input embedding: h = x @ W_in^T (MFMA, raw x w/ runtime dtype) ----------
__global__ __launch_bounds__(256) void gemm_in(const void* __restrict__ xraw,
                        const int* __restrict__ flags,
                        const unsigned short* __restrict__ Bin,
                        unsigned short* __restrict__ hout, int N)
{
    const int w = threadIdx.x >> 6, lane = threadIdx.x & 63;
    const int m = lane & 15, quad = lane >> 4;
    const int rowBase = blockIdx.x * 32;
    const bool abf = flags[0] != 0;
    f32x4 acc[2][2];
#pragma unroll
    for (int rt = 0; rt < 2; ++rt)
#pragma unroll
        for (int ct = 0; ct < 2; ++ct) acc[rt][ct] = (f32x4){0.f, 0.f, 0.f, 0.f};

#pragma unroll
    for (int ks = 0; ks < 2; ++ks) {
        bf16x8 a[2];
#pragma unroll
        for (int rt = 0; rt < 2; ++rt) {
            long row = rowBase + rt * 16 + m;
            if (abf) {
                a[rt] = *(const bf16x8*)(const void*)((const unsigned short*)xraw + row * 64 + ks * 32 + quad * 8);
            } else {
                const float* xp = (const float*)xraw + row * 64 + ks * 32 + quad * 8;
                float4 f0 = *(const float4*)xp;
                float4 f1 = *(const float4*)(xp + 4);
                bf16x8 t;
                t[0] = (short)f2bf(f0.x); t[1] = (short)f2bf(f0.y);
                t[2] = (short)f2bf(f0.z); t[3] = (short)f2bf(f0.w);
                t[4] = (short)f2bf(f1.x); t[5] = (short)f2bf(f1.y);
                t[6] = (short)f2bf(f1.z); t[7] = (short)f2bf(f1.w);
                a[rt] = t;
            }
        }
#pragma unroll
        for (int ct = 0; ct < 2; ++ct) {
            int t = w * 2 + ct;
            bf16x8 b = *(const bf16x8*)(const void*)(Bin + ((t * 2 + ks) * 64 + lane) * 8);
#pragma unroll
            for (int rt = 0; rt < 2; ++rt)
                acc[rt][ct] = __builtin_amdgcn_mfma_f32_16x16x32_bf16(a[rt], b, acc[rt][ct], 0, 0, 0);
        }
    }
#pragma unroll
    for (int rt = 0; rt < 2; ++rt)
#pragma unroll
        for (int ct = 0; ct < 2; ++ct)
#pragma unroll
            for (int reg = 0; reg < 4; ++reg) {
                int row = rowBase + rt * 16 + quad * 4 + reg;
                int col = w * 32 + ct * 16 + m;
                if (row < N) hout[(long)row * 128 + col] = f2bf(acc[rt][ct][reg]);
            }
}

// ---------- fused MPNN+GRU step: column-split persistent kernel ----------
// Block owns colgroup cg = blockIdx.x & 3 (32 original cols = 6 gate-permuted
// tiles). Stages its 6 Bci + 6 Bhh tiles (all 4 ks) = 48 KB LDS ONCE, then its
// 4 waves grid-stride over 32-row tiles with no barriers.
__global__ __launch_bounds__(256, 2) void step_kernel(
    const unsigned short* __restrict__ hin,
    const unsigned short* __restrict__ aggb,
    const unsigned short* __restrict__ Bci,
    const unsigned short* __restrict__ Bhh,
    const float* __restrict__ bip, const float* __restrict__ bhp,
    unsigned short* __restrict__ hout, int N, int ntiles, int nstreams)
{
    __shared__ unsigned short BS[2][12288];   // 48 KB: [mat][(ct*4+ks)*512 + lane*8]
    const int w = threadIdx.x >> 6, lane = threadIdx.x & 63;
    const int m = lane & 15, quad = lane >> 4;
    const int cg = blockIdx.x & 3;

    // one-time async stage of this colgroup's B tiles (all ks)
#pragma unroll
    for (int u = w; u < 24; u += 4) {
        int ct = u >> 2, ks = u & 3;
        long src = (((long)(cg * 6 + ct) * 4 + ks) * 64 + lane) * 8;
        gload_lds16(Bci + src, &BS[0][u * 512]);
        gload_lds16(Bhh + src, &BS[1][u * 512]);
    }

    // loop-invariant biases (gate-permuted)
    float bi[6], bh[6];
#pragma unroll
    for (int ct = 0; ct < 6; ++ct) {
        int nc = (cg * 6 + ct) * 16 + m;
        bi[ct] = bip[nc]; bh[ct] = bhp[nc];
    }

    __syncthreads();   // drain global_load_lds (compiler inserts vmcnt wait)

    const int t0 = (blockIdx.x >> 2) * 4 + w;
    for (int t = t0; t < ntiles; t += nstreams) {
        const long rowBase = (long)t * 32;
        f32x4 gi[2][6], gh[2][6];
#pragma unroll
        for (int ct = 0; ct < 6; ++ct)
#pragma unroll
            for (int rt = 0; rt < 2; ++rt) {
                gi[rt][ct] = (f32x4){bi[ct], bi[ct], bi[ct], bi[ct]};
                gh[rt][ct] = (f32x4){bh[ct], bh[ct], bh[ct], bh[ct]};
            }
#pragma unroll
        for (int ks = 0; ks < 4; ++ks) {
            bf16x8 aA[2], hA[2];
#pragma unroll
            for (int rt = 0; rt < 2; ++rt) {
                long row = rowBase + rt * 16 + m;
                aA[rt] = *(const bf16x8*)(const void*)(aggb + row * 128 + ks * 32 + quad * 8);
                hA[rt] = *(const bf16x8*)(const void*)(hin  + row * 128 + ks * 32 + quad * 8);
            }
#pragma unroll
            for (int ct = 0; ct < 6; ++ct) {
                bf16x8 bI = *(const bf16x8*)(const void*)&BS[0][(ct * 4 + ks) * 512 + lane * 8];
                bf16x8 bH = *(const bf16x8*)(const void*)&BS[1][(ct * 4 + ks) * 512 + lane * 8];
#pragma unroll
                for (int rt = 0; rt < 2; ++rt) {
                    gi[rt][ct] = __builtin_amdgcn_mfma_f32_16x16x32_bf16(aA[rt], bI, gi[rt][ct], 0, 0, 0);
                    gh[rt][ct] = __builtin_amdgcn_mfma_f32_16x16x32_bf16(hA[rt], bH, gh[rt][ct], 0, 0, 0);
                }
            }
        }
        // GRU epilogue for 32 rows x this colgroup's 32 original cols
#pragma unroll
        for (int rt = 0; rt < 2; ++rt)
#pragma unroll
            for (int half = 0; half < 2; ++half)
#pragma unroll
                for (int reg = 0; reg < 4; ++reg) {
                    long row = rowBase + rt * 16 + quad * 4 + reg;
                    if (row < N) {
                        int col = cg * 32 + half * 16 + m;
                        float R = 1.f / (1.f + __expf(-(gi[rt][half][reg]     + gh[rt][half][reg])));
                        float Z = 1.f / (1.f + __expf(-(gi[rt][2 + half][reg] + gh[rt][2 + half][reg])));
                        float Nn = tanhf(gi[rt][4 + half][reg] + R * gh[rt][4 + half][reg]);
                        float hold = bf2f(hin[row * 128 + col]);
                        hout[row * 128 + col] = f2bf((1.f - Z) * Nn + Z * hold);
                    }
                }
    }
}

// ---------- CSR build pass 1: radix partition into coarse buckets ----------
__global__ __launch_bounds__(256) void part1_kernel(
    const int* __restrict__ ei, int E, const int* __restrict__ flags,
    int* __restrict__ gcnt, uint2* __restrict__ pair2,
    int nb, int cshift, int ccap, int chunk)
{
    __shared__ int cnt[256];
    __shared__ int base_s[256];
    const int tid = threadIdx.x;
    if (tid < nb) cnt[tid] = 0;
    __syncthreads();
    const bool i64 = flags[1] != 0;
    const long long* e64 = (const long long*)ei;
    int lo = blockIdx.x * chunk;
    int hi = lo + chunk; if (hi > E) hi = E;
    for (int i = lo + tid; i < hi; i += 256) {
        int d = i64 ? (int)e64[(long)E + i] : ei[(long)E + i];
        atomicAdd(&cnt[d >> cshift], 1);
    }
    __syncthreads();
    if (tid < nb) {
        int c = cnt[tid];
        base_s[tid] = (c > 0) ? atomicAdd(&gcnt[tid], c) : 0;
        cnt[tid] = 0;
    }
    __syncthreads();
    for (int i = lo + tid; i < hi; i += 256) {
        int s, d;
        if (i64) { s = (int)e64[i]; d = (int)e64[(long)E + i]; }
        else     { s = ei[i];       d = ei[(long)E + i]; }
        int c = d >> cshift;
        int p = base_s[c] + atomicAdd(&cnt[c], 1);
        if (p < ccap) { uint2 pr; pr.x = (unsigned)s; pr.y = (unsigned)d; pair2[(long)c * ccap + p] = pr; }
    }
}

// exclusive scan of coarse-bucket counts (nb <= 256, single block)
__global__ void scanco_kernel(const int* __restrict__ gcnt, int* __restrict__ cbase,
                              int nb, int ccap)
{
    __shared__ int wsum[4];
    int tid = threadIdx.x, lane = tid & 63, wv = tid >> 6;
    int x = (tid < nb) ? gcnt[tid] : 0;
    if (x > ccap) x = ccap;
    int inc = x;
#pragma unroll
    for (int d = 1; d < 64; d <<= 1) { int u = __shfl_up(inc, d); if (lane >= d) inc += u; }
    if (lane == 63) wsum[wv] = inc;
    __syncthreads();
    if (tid == 0) { int s = 0; for (int q = 0; q < 4; ++q) { int t = wsum[q]; wsum[q] = s; s += t; } }
    __syncthreads();
    int excl = wsum[wv] + inc - x;
    if (tid < nb) cbase[tid] = excl;
    if (tid == nb - 1) cbase[nb] = excl + x;
}

// ---------- CSR build pass 2: per-coarse-bucket counting sort -> offs + csr ----------
__global__ __launch_bounds__(256) void part2_kernel(
    const uint2* __restrict__ pair2, const int* __restrict__ gcnt,
    const int* __restrict__ cbase,
    int* __restrict__ offs, int* __restrict__ csr,
    int N, int nb, int cshift, int ccap)
{
    __shared__ int lb[2048];
    __shared__ int wsum[4];
    const int b = blockIdx.x, tid = threadIdx.x;
    const int span = 1 << cshift;
    const int n0 = b << cshift;
    int count = gcnt[b]; if (count > ccap) count = ccap;
    for (int k = tid; k < span; k += 256) lb[k] = 0;
    __syncthreads();
    const uint2* pp = pair2 + (long)b * ccap;
    for (int i = tid; i < count; i += 256)
        atomicAdd(&lb[(int)pp[i].y - n0], 1);
    __syncthreads();
    int npe = span >> 8; if (npe < 1) npe = 1;
    int myb = tid * npe;
    int vals[8];
    int sum = 0;
    for (int k = 0; k < npe; ++k) { vals[k] = lb[myb + k]; sum += vals[k]; }
    int lane = tid & 63, wv = tid >> 6;
    int inc = sum;
#pragma unroll
    for (int d = 1; d < 64; d <<= 1) { int u = __shfl_up(inc, d); if (lane >= d) inc += u; }
    if (lane == 63) wsum[wv] = inc;
    __syncthreads();
    if (tid == 0) { int s = 0; for (int q = 0; q < 4; ++q) { int t = wsum[q]; wsum[q] = s; s += t; } }
    __syncthreads();
    int run = wsum[wv] + inc - sum;
    __syncthreads();
    for (int k = 0; k < npe; ++k) { lb[myb + k] = run; run += vals[k]; }
    __syncthreads();
    int gb = cbase[b];
    int nn = N - n0; if (nn > span) nn = span;
    for (int g = tid; g < nn; g += 256) offs[n0 + g] = gb + lb[g];
    if (b == nb - 1 && tid == 0) offs[N] = cbase[nb];
    __syncthreads();
    for (int i = tid; i < count; i += 256) {
        uint2 pr = pp[i];
        int p = gb + atomicAdd(&lb[(int)pr.y - n0], 1);
        csr[p] = (int)pr.x;
    }
}

// ---------- aggregation (bf16, 16B/lane, 16 gathers in flight per wave) ----------
__global__ __launch_bounds__(256) void aggregate(const unsigned short* __restrict__ hb,
                          const int* __restrict__ off,
                          const int* __restrict__ csr,
                          unsigned short* __restrict__ aggb, int n)
{
    int wv = threadIdx.x >> 6, lane = threadIdx.x & 63;
    int node = blockIdx.x * 4 + wv;
    if (node >= n) return;
    int s0 = off[node], s1 = off[node + 1];
    int slot = lane >> 4;
    int c16 = lane & 15;
    float a0 = 0.f, a1 = 0.f, a2 = 0.f, a3 = 0.f, a4 = 0.f, a5 = 0.f, a6 = 0.f, a7 = 0.f;
    int j = s0 + slot;
    for (; j + 12 < s1; j += 16) {
        int iA = csr[j], iB = csr[j + 4], iC = csr[j + 8], iD = csr[j + 12];
        uint4 v0 = *(const uint4*)(const void*)(hb + (long)iA * 128 + c16 * 8);
        uint4 v1 = *(const uint4*)(const void*)(hb + (long)iB * 128 + c16 * 8);
        uint4 v2 = *(const uint4*)(const void*)(hb + (long)iC * 128 + c16 * 8);
        uint4 v3 = *(const uint4*)(const void*)(hb + (long)iD * 128 + c16 * 8);
        a0 += bflo(v0.x); a1 += bfhi(v0.x); a2 += bflo(v0.y); a3 += bfhi(v0.y);
        a4 += bflo(v0.z); a5 += bfhi(v0.z); a6 += bflo(v0.w); a7 += bfhi(v0.w);
        a0 += bflo(v1.x); a1 += bfhi(v1.x); a2 += bflo(v1.y); a3 += bfhi(v1.y);
        a4 += bflo(v1.z); a5 += bfhi(v1.z); a6 += bflo(v1.w); a7 += bfhi(v1.w);
        a0 += bflo(v2.x); a1 += bfhi(v2.x); a2 += bflo(v2.y); a3 += bfhi(v2.y);
        a4 += bflo(v2.z); a5 += bfhi(v2.z); a6 += bflo(v2.w); a7 += bfhi(v2.w);
        a0 += bflo(v3.x); a1 += bfhi(v3.x); a2 += bflo(v3.y); a3 += bfhi(v3.y);
        a4 += bflo(v3.z); a5 += bfhi(v3.z); a6 += bflo(v3.w); a7 += bfhi(v3.w);
    }
    for (; j < s1; j += 4) {
        int sA = csr[j];
        uint4 v1 = *(const uint4*)(const void*)(hb + (long)sA * 128 + c16 * 8);
        a0 += bflo(v1.x); a1 += bfhi(v1.x); a2 += bflo(v1.y); a3 += bfhi(v1.y);
        a4 += bflo(v1.z); a5 += bfhi(v1.z); a6 += bflo(v1.w); a7 += bfhi(v1.w);
    }
    a0 += __shfl_xor(a0, 16); a1 += __shfl_xor(a1, 16);
    a2 += __shfl_xor(a2, 16); a3 += __shfl_xor(a3, 16);
    a4 += __shfl_xor(a4, 16); a5 += __shfl_xor(a5, 16);
    a6 += __shfl_xor(a6, 16); a7 += __shfl_xor(a7, 16);
    a0 += __shfl_xor(a0, 32); a1 += __shfl_xor(a1, 32);
    a2 += __shfl_xor(a2, 32); a3 += __shfl_xor(a3, 32);
    a4 += __shfl_xor(a4, 32); a5 += __shfl_xor(a5, 32);
    a6 += __shfl_xor(a6, 32); a7 += __shfl_xor(a7, 32);
    if (slot == 0) {
        uint4 o;
        o.x = ((unsigned int)f2bf(a1) << 16) | f2bf(a0);
        o.y = ((unsigned int)f2bf(a3) << 16) | f2bf(a2);
        o.z = ((unsigned int)f2bf(a5) << 16) | f2bf(a4);
        o.w = ((unsigned int)f2bf(a7) << 16) | f2bf(a6);
        *(uint4*)(void*)(aggb + (long)node * 128 + c16 * 8) = o;
    }
}

// ---------- readout ----------
__global__ void colsum(const unsigned short* __restrict__ hb, float* __restrict__ acc, int n) {
    int c = threadIdx.x & 127;
    int sub = threadIdx.x >> 7;
    float local = 0.f;
    for (long r = blockIdx.x * 2 + sub; r < n; r += (long)gridDim.x * 2) {
        float v = bf2f(hb[r * 128 + c]);
        local += (v >= 0.f) ? v : 0.01f * v;
    }
    atomicAdd(&acc[c], local);
}

__global__ void finalize(const float* __restrict__ acc,
                         const float* __restrict__ W_pred_f,
                         const float* __restrict__ b_pred_f,
                         unsigned int* __restrict__ out, float invN)
{
    __shared__ float ws2[2];
    int t = threadIdx.x;  // 128 threads
    float v = acc[t] * invN * W_pred_f[t];
#pragma unroll
    for (int d = 32; d >= 1; d >>= 1) v += __shfl_down(v, d);
    if ((t & 63) == 0) ws2[t >> 6] = v;
    __syncthreads();
    if (t == 0) {
        float r = ws2[0] + ws2[1] + b_pred_f[0];
        unsigned int bf = (unsigned int)f2bf(r);
        out[0] = (bf << 16) | bf;   // dual-dtype store
    }
}

// ---------- host ----------
extern "C" void kernel_launch(void* const* d_in, const int* in_sizes, int n_in,
                              void* d_out, int out_size, void* d_ws, size_t ws_size,
                              hipStream_t stream)
{
    const void* x      = d_in[0];
    const int*  ei     = (const int*)d_in[1];
    const void* W_in   = d_in[2];
    const void* W_mpnn = d_in[3];
    const void* W_ih   = d_in[4];
    const void* W_hh   = d_in[5];
    const void* b_ih   = d_in[6];
    const void* b_hh   = d_in[7];
    const void* W_pred = d_in[8];
    const void* b_pred = d_in[9];

    const int N = in_sizes[0] / 64;              // 100000
    const int E = in_sizes[1] / 2;               // 1600000
    const int STEPS = in_sizes[3] / (128 * 128); // 4

    int cshift = 9;
    while ((((N + (1 << cshift) - 1) >> cshift)) > 256 && cshift < 11) cshift++;
    const int NCO = (N + (1 << cshift) - 1) >> cshift;
    const int ccap = (((E / NCO) * 3 / 2 + 1024) + 255) & ~255;
    const int chunk = (E + 255) / 256;
    const int ntiles = (N + 31) / 32;
    const int NBLK = 768;                         // 192 blocks x 4 waves per colgroup
    const int nstreams = (NBLK / 4) * 4;          // row-streams per colgroup

    size_t woff = 0;
    auto carve = [&](size_t bytes) -> void* {
        void* p = (char*)d_ws + woff;
        woff = (woff + bytes + 255) & ~(size_t)255;
        return p;
    };
    int*   flags = (int*)carve(2 * 4);
    float* Winf  = (float*)carve(8192 * 4);
    float* Wmf   = (float*)carve((size_t)STEPS * 16384 * 4);
    float* Wihf  = (float*)carve(49152 * 4);
    float* Whhf  = (float*)carve(49152 * 4);
    float* bihf  = (float*)carve(384 * 4);
    float* bhhf  = (float*)carve(384 * 4);
    float* Wpf   = (float*)carve(128 * 4);
    float* bpf   = (float*)carve(4);
    float* Wcomb = (float*)carve((size_t)STEPS * 49152 * 4);
    unsigned short* Bci = (unsigned short*)carve((size_t)STEPS * 49152 * 2);
    unsigned short* Bhh = (unsigned short*)carve(49152 * 2);
    unsigned short* Bin = (unsigned short*)carve(8192 * 2);
    float* bip   = (float*)carve(384 * 4);
    float* bhp   = (float*)carve(384 * 4);
    unsigned short* hA   = (unsigned short*)carve(((size_t)N * 128 + 16384) * 2);
    unsigned short* hB   = (unsigned short*)carve(((size_t)N * 128 + 16384) * 2);
    unsigned short* aggb = (unsigned short*)carve(((size_t)N * 128 + 16384) * 2);
    int*   gcnt  = (int*)carve(256 * 4);
    int*   cbase = (int*)carve(257 * 4);
    int*   offs  = (int*)carve((size_t)(N + 1) * 4);
    int*   csr   = (int*)carve((size_t)E * 4);
    uint2* pair2 = (uint2*)carve((size_t)NCO * ccap * 8);
    float* accb  = (float*)carve(128 * 4);

    hipMemsetAsync(gcnt, 0, 256 * 4, stream);
    hipMemsetAsync(accb, 0, 128 * 4, stream);

    detect_kernel<<<1, 256, 0, stream>>>((const unsigned int*)x, ei, flags);

    {
        int total = 8192 + STEPS * 16384 + 2 * 49152 + 768 + 129;
        convall_kernel<<<(total + 255) / 256, 256, 0, stream>>>(
            W_in, W_mpnn, W_ih, W_hh, b_ih, b_hh, W_pred, b_pred,
            Winf, Wmf, Wihf, Whhf, bihf, bhhf, Wpf, bpf, STEPS, flags);
    }

    wcomb_kernel<<<(STEPS * 49152 + 255) / 256, 256, 0, stream>>>(Wmf, Wihf, Wcomb, STEPS);
    {
        int total = (STEPS + 1) * 49152 + 768;
        pack_gates<<<(total + 255) / 256, 256, 0, stream>>>(Wcomb, Whhf, bihf, bhhf,
                                                            Bci, Bhh, bip, bhp, STEPS);
    }
    pack_in<<<32, 256, 0, stream>>>(Winf, Bin);

    // h0 = x @ W_in^T (reads raw x, runtime dtype)
    gemm_in<<<(N + 31) / 32, 256, 0, stream>>>(x, flags, Bin, hA, N);

    // CSR build: radix partition -> coarse scan -> per-bucket counting sort
    part1_kernel<<<256, 256, 0, stream>>>(ei, E, flags, gcnt, pair2, NCO, cshift, ccap, chunk);
    scanco_kernel<<<1, 256, 0, stream>>>(gcnt, cbase, NCO, ccap);
    part2_kernel<<<NCO, 256, 0, stream>>>(pair2, gcnt, cbase, offs, csr, N, NCO, cshift, ccap);

    unsigned short* hcur = hA;
    unsigned short* hnxt = hB;
    for (int step = 0; step < STEPS; ++step) {
        aggregate<<<(N + 3) / 4, 256, 0, stream>>>(hcur, offs, csr, aggb, N);
        step_kernel<<<NBLK, 256, 0, stream>>>(
            hcur, aggb, Bci + (size_t)step * 49152, Bhh, bip, bhp, hnxt, N, ntiles, nstreams);
        unsigned short* t = hcur; hcur = hnxt; hnxt = t;
    }

    colsum<<<512, 256, 0, stream>>>(hcur, accb, N);
    finalize<<<1, 128, 0, stream>>>(accb, Wpf, bpf, (unsigned int*)d_out, 1.f / (float)N);
}

// Round 9
// 810.821 us; speedup vs baseline: 1.4911x; 1.4911x over previous
//
#include <hip/hip_runtime.h>
#include <cstdint>

typedef __attribute__((ext_vector_type(8))) short bf16x8;
typedef __attribute__((ext_vector_type(4))) float f32x4;

// ---------- helpers ----------
__device__ __forceinline__ float bf2f(unsigned short u) {
    union { unsigned int i; float f; } v; v.i = ((unsigned int)u) << 16; return v.f;
}
__device__ __forceinline__ float bfhi(unsigned int w) {
    union { unsigned int i; float f; } v; v.i = w & 0xffff0000u; return v.f;
}
__device__ __forceinline__ float bflo(unsigned int w) {
    union { unsigned int i; float f; } v; v.i = w << 16; return v.f;
}
__device__ __forceinline__ unsigned short f2bf(float f) {
    union { float ff; unsigned int i; } v; v.ff = f;
    unsigned int r = (v.i + 0x7fffu + ((v.i >> 16) & 1u)) >> 16;
    return (unsigned short)r;
}
// gate-permuted column -> original column (nc in [0,384))
__device__ __forceinline__ int origcol(int nc) {
    int w = nc / 96, rem = nc % 96, g = rem / 32, cc = rem % 32;
    return g * 128 + w * 32 + cc;
}

// ---------- runtime dtype detection ----------
__global__ void detect_kernel(const unsigned int* __restrict__ x32,
                              const int* __restrict__ ei32,
                              int* __restrict__ flags)
{
    __shared__ int insaneS;
    __shared__ int orS;
    int tid = threadIdx.x;
    if (tid == 0) { insaneS = 0; orS = 0; }
    __syncthreads();
    int insane = 0;
    for (int j = tid; j < 512; j += 256) {
        unsigned int w = x32[j];
        int e = (int)((w >> 7) & 0xFF);
        if (e > 135 || e < 100) insane++;
    }
    int ov = 0;
    for (int j = tid; j < 256; j += 256) ov |= ei32[2 * j + 1];
    atomicAdd(&insaneS, insane);
    atomicOr(&orS, ov);
    __syncthreads();
    if (tid == 0) {
        flags[0] = (insaneS < 64) ? 1 : 0;   // 1 = bf16-packed floats
        flags[1] = (orS == 0) ? 1 : 0;       // 1 = int64 edges
    }
}

// ---------- all-weights conversion (bf16-or-f32 -> f32), one launch ----------
__global__ void convall_kernel(const void* W_in, const void* W_mpnn, const void* W_ih,
                               const void* W_hh, const void* b_ih, const void* b_hh,
                               const void* W_pred, const void* b_pred,
                               float* __restrict__ Winf, float* __restrict__ Wmf,
                               float* __restrict__ Wihf, float* __restrict__ Whhf,
                               float* __restrict__ bihf, float* __restrict__ bhhf,
                               float* __restrict__ Wpf, float* __restrict__ bpf,
                               int steps, const int* __restrict__ flags)
{
    int i = blockIdx.x * 256 + threadIdx.x;
    int bf = flags[0];
    auto get = [&](const void* p, int idx) -> float {
        return bf ? bf2f(((const unsigned short*)p)[idx]) : ((const float*)p)[idx];
    };
    int n0 = 8192, n1 = n0 + steps * 16384, n2 = n1 + 49152, n3 = n2 + 49152;
    int n4 = n3 + 384, n5 = n4 + 384, n6 = n5 + 128, n7 = n6 + 1;
    if      (i < n0) Winf[i]      = get(W_in,   i);
    else if (i < n1) Wmf[i - n0]  = get(W_mpnn, i - n0);
    else if (i < n2) Wihf[i - n1] = get(W_ih,   i - n1);
    else if (i < n3) Whhf[i - n2] = get(W_hh,   i - n2);
    else if (i < n4) bihf[i - n3] = get(b_ih,   i - n3);
    else if (i < n5) bhhf[i - n4] = get(b_hh,   i - n4);
    else if (i < n6) Wpf[i - n5]  = get(W_pred, i - n5);
    else if (i < n7) bpf[i - n6]  = get(b_pred, i - n6);
}

// Wcomb[step][k][j] = sum_t W_mpnn[step][k][t] * W_ih[j][t]   ([steps][128][384])
__global__ void wcomb_kernel(const float* __restrict__ Wm,
                             const float* __restrict__ Wih,
                             float* __restrict__ Wcomb, int steps)
{
    int i = blockIdx.x * 256 + threadIdx.x;
    int total = steps * 49152;
    if (i >= total) return;
    int step = i / 49152;
    int rem = i - step * 49152;
    int k = rem / 384;
    int j = rem - k * 384;
    const float* wm = Wm + ((long)step * 128 + k) * 128;
    const float* wi = Wih + (long)j * 128;
    float s = 0.f;
#pragma unroll 8
    for (int t = 0; t < 128; ++t) s += wm[t] * wi[t];
    Wcomb[i] = s;
}

// ---------- pack weights into MFMA-fragment-ready bf16 layout ----------
__global__ void pack_gates(const float* __restrict__ Wcomb,
                           const float* __restrict__ Whhf,
                           const float* __restrict__ bihf, const float* __restrict__ bhhf,
                           unsigned short* __restrict__ Bci,
                           unsigned short* __restrict__ Bhh,
                           float* __restrict__ bip, float* __restrict__ bhp,
                           int steps)
{
    int i = blockIdx.x * 256 + threadIdx.x;
    int nmat = steps * 49152;
    if (i < nmat) {
        int s = i / 49152, r = i - s * 49152;
        int t = r >> 11, rem = r & 2047;
        int ks = rem >> 9, l = (rem >> 3) & 63, j = rem & 7;
        int k = ks * 32 + (l >> 4) * 8 + j;
        int oc = origcol(t * 16 + (l & 15));
        Bci[i] = f2bf(Wcomb[(long)s * 49152 + k * 384 + oc]);
    } else if (i < nmat + 49152) {
        int r = i - nmat;
        int t = r >> 11, rem = r & 2047;
        int ks = rem >> 9, l = (rem >> 3) & 63, j = rem & 7;
        int k = ks * 32 + (l >> 4) * 8 + j;
        int oc = origcol(t * 16 + (l & 15));
        Bhh[r] = f2bf(Whhf[(long)oc * 128 + k]);
    } else if (i < nmat + 49152 + 768) {
        int b = i - nmat - 49152;
        if (b < 384) bip[b] = bihf[origcol(b)];
        else         bhp[b - 384] = bhhf[origcol(b - 384)];
    }
}

// pack W_in ([128][64] row-major fp32) -> [8 t][2 ks][64][8] bf16
__global__ void pack_in(const float* __restrict__ Winf, unsigned short* __restrict__ Bin)
{
    int r = blockIdx.x * 256 + threadIdx.x;
    if (r >= 8192) return;
    int t = r >> 10, rem = r & 1023;
    int ks = rem >> 9, l = (rem >> 3) & 63, j = rem & 7;
    int k = ks * 32 + (l >> 4) * 8 + j;
    int col = t * 16 + (l & 15);
    Bin[r] = f2bf(Winf[col * 64 + k]);
}

// ---------- input embedding: h = x @ W_in^T (MFMA, raw x w/ runtime dtype) ----------
__global__ __launch_bounds__(256) void gemm_in(const void* __restrict__ xraw,
                        const int* __restrict__ flags,
                        const unsigned short* __restrict__ Bin,
                        unsigned short* __restrict__ hout, int N)
{
    const int w = threadIdx.x >> 6, lane = threadIdx.x & 63;
    const int m = lane & 15, quad = lane >> 4;
    const int rowBase = blockIdx.x * 32;
    const bool abf = flags[0] != 0;
    f32x4 acc[2][2];
#pragma unroll
    for (int rt = 0; rt < 2; ++rt)
#pragma unroll
        for (int ct = 0; ct < 2; ++ct) acc[rt][ct] = (f32x4){0.f, 0.f, 0.f, 0.f};

#pragma unroll
    for (int ks = 0; ks < 2; ++ks) {
        bf16x8 a[2];
#pragma unroll
        for (int rt = 0; rt < 2; ++rt) {
            long row = rowBase + rt * 16 + m;
            if (abf) {
                a[rt] = *(const bf16x8*)(const void*)((const unsigned short*)xraw + row * 64 + ks * 32 + quad * 8);
            } else {
                const float* xp = (const float*)xraw + row * 64 + ks * 32 + quad * 8;
                float4 f0 = *(const float4*)xp;
                float4 f1 = *(const float4*)(xp + 4);
                bf16x8 t;
                t[0] = (short)f2bf(f0.x); t[1] = (short)f2bf(f0.y);
                t[2] = (short)f2bf(f0.z); t[3] = (short)f2bf(f0.w);
                t[4] = (short)f2bf(f1.x); t[5] = (short)f2bf(f1.y);
                t[6] = (short)f2bf(f1.z); t[7] = (short)f2bf(f1.w);
                a[rt] = t;
            }
        }
#pragma unroll
        for (int ct = 0; ct < 2; ++ct) {
            int t = w * 2 + ct;
            bf16x8 b = *(const bf16x8*)(const void*)(Bin + ((t * 2 + ks) * 64 + lane) * 8);
#pragma unroll
            for (int rt = 0; rt < 2; ++rt)
                acc[rt][ct] = __builtin_amdgcn_mfma_f32_16x16x32_bf16(a[rt], b, acc[rt][ct], 0, 0, 0);
        }
    }
#pragma unroll
    for (int rt = 0; rt < 2; ++rt)
#pragma unroll
        for (int ct = 0; ct < 2; ++ct)
#pragma unroll
            for (int reg = 0; reg < 4; ++reg) {
                int row = rowBase + rt * 16 + quad * 4 + reg;
                int col = w * 32 + ct * 16 + m;
                if (row < N) hout[(long)row * 128 + col] = f2bf(acc[rt][ct][reg]);
            }
}

// ---------- fused MPNN+GRU step: thin-wave (512 thr, 3 gate-tiles/wave) ----------
// Wave w = cg*2+half owns gate-tiles t = cg*6 + g*2 + half (g=0,1,2) -> a full
// (r,z,n) triplet for cols [cg*32+half*16, +16). No LDS, no barriers; B frags
// straight from global (L1/L2-resident, identical across blocks). 48 acc VGPRs.
__global__ __launch_bounds__(512, 4) void step_kernel(
    const unsigned short* __restrict__ hin,
    const unsigned short* __restrict__ aggb,
    const unsigned short* __restrict__ Bci,
    const unsigned short* __restrict__ Bhh,
    const float* __restrict__ bip, const float* __restrict__ bhp,
    unsigned short* __restrict__ hout, int N)
{
    const int w = threadIdx.x >> 6, lane = threadIdx.x & 63;
    const int m = lane & 15, quad = lane >> 4;
    const int cg = w >> 1, half = w & 1;
    const long rowBase = (long)blockIdx.x * 32;

    f32x4 gi[2][3], gh[2][3];
#pragma unroll
    for (int g = 0; g < 3; ++g) {
        int nc = (cg * 6 + g * 2 + half) * 16 + m;
        float bi = bip[nc], bh = bhp[nc];
#pragma unroll
        for (int rt = 0; rt < 2; ++rt) {
            gi[rt][g] = (f32x4){bi, bi, bi, bi};
            gh[rt][g] = (f32x4){bh, bh, bh, bh};
        }
    }

#pragma unroll
    for (int ks = 0; ks < 4; ++ks) {
        bf16x8 aA[2], hA[2];
#pragma unroll
        for (int rt = 0; rt < 2; ++rt) {
            long row = rowBase + rt * 16 + m;
            aA[rt] = *(const bf16x8*)(const void*)(aggb + row * 128 + ks * 32 + quad * 8);
            hA[rt] = *(const bf16x8*)(const void*)(hin  + row * 128 + ks * 32 + quad * 8);
        }
#pragma unroll
        for (int g = 0; g < 3; ++g) {
            int t = cg * 6 + g * 2 + half;
            bf16x8 bI = *(const bf16x8*)(const void*)(Bci + (((long)t * 4 + ks) * 64 + lane) * 8);
            bf16x8 bH = *(const bf16x8*)(const void*)(Bhh + (((long)t * 4 + ks) * 64 + lane) * 8);
#pragma unroll
            for (int rt = 0; rt < 2; ++rt) {
                gi[rt][g] = __builtin_amdgcn_mfma_f32_16x16x32_bf16(aA[rt], bI, gi[rt][g], 0, 0, 0);
                gh[rt][g] = __builtin_amdgcn_mfma_f32_16x16x32_bf16(hA[rt], bH, gh[rt][g], 0, 0, 0);
            }
        }
    }

    // GRU epilogue: g=0 -> r, g=1 -> z, g=2 -> n; cols cg*32+half*16+m
#pragma unroll
    for (int rt = 0; rt < 2; ++rt)
#pragma unroll
        for (int reg = 0; reg < 4; ++reg) {
            long row = rowBase + rt * 16 + quad * 4 + reg;
            if (row < N) {
                int col = cg * 32 + half * 16 + m;
                float R  = 1.f / (1.f + __expf(-(gi[rt][0][reg] + gh[rt][0][reg])));
                float Z  = 1.f / (1.f + __expf(-(gi[rt][1][reg] + gh[rt][1][reg])));
                float Nn = tanhf(gi[rt][2][reg] + R * gh[rt][2][reg]);
                float hold = bf2f(hin[row * 128 + col]);
                hout[row * 128 + col] = f2bf((1.f - Z) * Nn + Z * hold);
            }
        }
}

// ---------- CSR build pass 1: radix partition into coarse buckets ----------
__global__ __launch_bounds__(256) void part1_kernel(
    const int* __restrict__ ei, int E, const int* __restrict__ flags,
    int* __restrict__ gcnt, uint2* __restrict__ pair2,
    int nb, int cshift, int ccap, int chunk)
{
    __shared__ int cnt[256];
    __shared__ int base_s[256];
    const int tid = threadIdx.x;
    if (tid < nb) cnt[tid] = 0;
    __syncthreads();
    const bool i64 = flags[1] != 0;
    const long long* e64 = (const long long*)ei;
    int lo = blockIdx.x * chunk;
    int hi = lo + chunk; if (hi > E) hi = E;
    for (int i = lo + tid; i < hi; i += 256) {
        int d = i64 ? (int)e64[(long)E + i] : ei[(long)E + i];
        atomicAdd(&cnt[d >> cshift], 1);
    }
    __syncthreads();
    if (tid < nb) {
        int c = cnt[tid];
        base_s[tid] = (c > 0) ? atomicAdd(&gcnt[tid], c) : 0;
        cnt[tid] = 0;
    }
    __syncthreads();
    for (int i = lo + tid; i < hi; i += 256) {
        int s, d;
        if (i64) { s = (int)e64[i]; d = (int)e64[(long)E + i]; }
        else     { s = ei[i];       d = ei[(long)E + i]; }
        int c = d >> cshift;
        int p = base_s[c] + atomicAdd(&cnt[c], 1);
        if (p < ccap) { uint2 pr; pr.x = (unsigned)s; pr.y = (unsigned)d; pair2[(long)c * ccap + p] = pr; }
    }
}

// exclusive scan of coarse-bucket counts (nb <= 256, single block)
__global__ void scanco_kernel(const int* __restrict__ gcnt, int* __restrict__ cbase,
                              int nb, int ccap)
{
    __shared__ int wsum[4];
    int tid = threadIdx.x, lane = tid & 63, wv = tid >> 6;
    int x = (tid < nb) ? gcnt[tid] : 0;
    if (x > ccap) x = ccap;
    int inc = x;
#pragma unroll
    for (int d = 1; d < 64; d <<= 1) { int u = __shfl_up(inc, d); if (lane >= d) inc += u; }
    if (lane == 63) wsum[wv] = inc;
    __syncthreads();
    if (tid == 0) { int s = 0; for (int q = 0; q < 4; ++q) { int t = wsum[q]; wsum[q] = s; s += t; } }
    __syncthreads();
    int excl = wsum[wv] + inc - x;
    if (tid < nb) cbase[tid] = excl;
    if (tid == nb - 1) cbase[nb] = excl + x;
}

// ---------- CSR build pass 2: per-coarse-bucket counting sort -> offs + csr ----------
__global__ __launch_bounds__(256) void part2_kernel(
    const uint2* __restrict__ pair2, const int* __restrict__ gcnt,
    const int* __restrict__ cbase,
    int* __restrict__ offs, int* __restrict__ csr,
    int N, int nb, int cshift, int ccap)
{
    __shared__ int lb[2048];
    __shared__ int wsum[4];
    const int b = blockIdx.x, tid = threadIdx.x;
    const int span = 1 << cshift;
    const int n0 = b << cshift;
    int count = gcnt[b]; if (count > ccap) count = ccap;
    for (int k = tid; k < span; k += 256) lb[k] = 0;
    __syncthreads();
    const uint2* pp = pair2 + (long)b * ccap;
    for (int i = tid; i < count; i += 256)
        atomicAdd(&lb[(int)pp[i].y - n0], 1);
    __syncthreads();
    int npe = span >> 8; if (npe < 1) npe = 1;
    int myb = tid * npe;
    int vals[8];
    int sum = 0;
    for (int k = 0; k < npe; ++k) { vals[k] = lb[myb + k]; sum += vals[k]; }
    int lane = tid & 63, wv = tid >> 6;
    int inc = sum;
#pragma unroll
    for (int d = 1; d < 64; d <<= 1) { int u = __shfl_up(inc, d); if (lane >= d) inc += u; }
    if (lane == 63) wsum[wv] = inc;
    __syncthreads();
    if (tid == 0) { int s = 0; for (int q = 0; q < 4; ++q) { int t = wsum[q]; wsum[q] = s; s += t; } }
    __syncthreads();
    int run = wsum[wv] + inc - sum;
    __syncthreads();
    for (int k = 0; k < npe; ++k) { lb[myb + k] = run; run += vals[k]; }
    __syncthreads();
    int gb = cbase[b];
    int nn = N - n0; if (nn > span) nn = span;
    for (int g = tid; g < nn; g += 256) offs[n0 + g] = gb + lb[g];
    if (b == nb - 1 && tid == 0) offs[N] = cbase[nb];
    __syncthreads();
    for (int i = tid; i < count; i += 256) {
        uint2 pr = pp[i];
        int p = gb + atomicAdd(&lb[(int)pr.y - n0], 1);
        csr[p] = (int)pr.x;
    }
}

// ---------- aggregation (bf16, 16B/lane, 16 gathers in flight per wave) ----------
__global__ __launch_bounds__(256) void aggregate(const unsigned short* __restrict__ hb,
                          const int* __restrict__ off,
                          const int* __restrict__ csr,
                          unsigned short* __restrict__ aggb, int n)
{
    int wv = threadIdx.x >> 6, lane = threadIdx.x & 63;
    int node = blockIdx.x * 4 + wv;
    if (node >= n) return;
    int s0 = off[node], s1 = off[node + 1];
    int slot = lane >> 4;
    int c16 = lane & 15;
    float a0 = 0.f, a1 = 0.f, a2 = 0.f, a3 = 0.f, a4 = 0.f, a5 = 0.f, a6 = 0.f, a7 = 0.f;
    int j = s0 + slot;
    for (; j + 12 < s1; j += 16) {
        int iA = csr[j], iB = csr[j + 4], iC = csr[j + 8], iD = csr[j + 12];
        uint4 v0 = *(const uint4*)(const void*)(hb + (long)iA * 128 + c16 * 8);
        uint4 v1 = *(const uint4*)(const void*)(hb + (long)iB * 128 + c16 * 8);
        uint4 v2 = *(const uint4*)(const void*)(hb + (long)iC * 128 + c16 * 8);
        uint4 v3 = *(const uint4*)(const void*)(hb + (long)iD * 128 + c16 * 8);
        a0 += bflo(v0.x); a1 += bfhi(v0.x); a2 += bflo(v0.y); a3 += bfhi(v0.y);
        a4 += bflo(v0.z); a5 += bfhi(v0.z); a6 += bflo(v0.w); a7 += bfhi(v0.w);
        a0 += bflo(v1.x); a1 += bfhi(v1.x); a2 += bflo(v1.y); a3 += bfhi(v1.y);
        a4 += bflo(v1.z); a5 += bfhi(v1.z); a6 += bflo(v1.w); a7 += bfhi(v1.w);
        a0 += bflo(v2.x); a1 += bfhi(v2.x); a2 += bflo(v2.y); a3 += bfhi(v2.y);
        a4 += bflo(v2.z); a5 += bfhi(v2.z); a6 += bflo(v2.w); a7 += bfhi(v2.w);
        a0 += bflo(v3.x); a1 += bfhi(v3.x); a2 += bflo(v3.y); a3 += bfhi(v3.y);
        a4 += bflo(v3.z); a5 += bfhi(v3.z); a6 += bflo(v3.w); a7 += bfhi(v3.w);
    }
    for (; j < s1; j += 4) {
        int sA = csr[j];
        uint4 v1 = *(const uint4*)(const void*)(hb + (long)sA * 128 + c16 * 8);
        a0 += bflo(v1.x); a1 += bfhi(v1.x); a2 += bflo(v1.y); a3 += bfhi(v1.y);
        a4 += bflo(v1.z); a5 += bfhi(v1.z); a6 += bflo(v1.w); a7 += bfhi(v1.w);
    }
    a0 += __shfl_xor(a0, 16); a1 += __shfl_xor(a1, 16);
    a2 += __shfl_xor(a2, 16); a3 += __shfl_xor(a3, 16);
    a4 += __shfl_xor(a4, 16); a5 += __shfl_xor(a5, 16);
    a6 += __shfl_xor(a6, 16); a7 += __shfl_xor(a7, 16);
    a0 += __shfl_xor(a0, 32); a1 += __shfl_xor(a1, 32);
    a2 += __shfl_xor(a2, 32); a3 += __shfl_xor(a3, 32);
    a4 += __shfl_xor(a4, 32); a5 += __shfl_xor(a5, 32);
    a6 += __shfl_xor(a6, 32); a7 += __shfl_xor(a7, 32);
    if (slot == 0) {
        uint4 o;
        o.x = ((unsigned int)f2bf(a1) << 16) | f2bf(a0);
        o.y = ((unsigned int)f2bf(a3) << 16) | f2bf(a2);
        o.z = ((unsigned int)f2bf(a5) << 16) | f2bf(a4);
        o.w = ((unsigned int)f2bf(a7) << 16) | f2bf(a6);
        *(uint4*)(void*)(aggb + (long)node * 128 + c16 * 8) = o;
    }
}

// ---------- readout ----------
__global__ void colsum(const unsigned short* __restrict__ hb, float* __restrict__ acc, int n) {
    int c = threadIdx.x & 127;
    int sub = threadIdx.x >> 7;
    float local = 0.f;
    for (long r = blockIdx.x * 2 + sub; r < n; r += (long)gridDim.x * 2) {
        float v = bf2f(hb[r * 128 + c]);
        local += (v >= 0.f) ? v : 0.01f * v;
    }
    atomicAdd(&acc[c], local);
}

__global__ void finalize(const float* __restrict__ acc,
                         const float* __restrict__ W_pred_f,
                         const float* __restrict__ b_pred_f,
                         unsigned int* __restrict__ out, float invN)
{
    __shared__ float ws2[2];
    int t = threadIdx.x;  // 128 threads
    float v = acc[t] * invN * W_pred_f[t];
#pragma unroll
    for (int d = 32; d >= 1; d >>= 1) v += __shfl_down(v, d);
    if ((t & 63) == 0) ws2[t >> 6] = v;
    __syncthreads();
    if (t == 0) {
        float r = ws2[0] + ws2[1] + b_pred_f[0];
        unsigned int bf = (unsigned int)f2bf(r);
        out[0] = (bf << 16) | bf;   // dual-dtype store
    }
}

// ---------- host ----------
extern "C" void kernel_launch(void* const* d_in, const int* in_sizes, int n_in,
                              void* d_out, int out_size, void* d_ws, size_t ws_size,
                              hipStream_t stream)
{
    const void* x      = d_in[0];
    const int*  ei     = (const int*)d_in[1];
    const void* W_in   = d_in[2];
    const void* W_mpnn = d_in[3];
    const void* W_ih   = d_in[4];
    const void* W_hh   = d_in[5];
    const void* b_ih   = d_in[6];
    const void* b_hh   = d_in[7];
    const void* W_pred = d_in[8];
    const void* b_pred = d_in[9];

    const int N = in_sizes[0] / 64;              // 100000
    const int E = in_sizes[1] / 2;               // 1600000
    const int STEPS = in_sizes[3] / (128 * 128); // 4

    int cshift = 9;
    while ((((N + (1 << cshift) - 1) >> cshift)) > 256 && cshift < 11) cshift++;
    const int NCO = (N + (1 << cshift) - 1) >> cshift;
    const int ccap = (((E / NCO) * 3 / 2 + 1024) + 255) & ~255;
    const int chunk = (E + 255) / 256;

    size_t woff = 0;
    auto carve = [&](size_t bytes) -> void* {
        void* p = (char*)d_ws + woff;
        woff = (woff + bytes + 255) & ~(size_t)255;
        return p;
    };
    int*   flags = (int*)carve(2 * 4);
    float* Winf  = (float*)carve(8192 * 4);
    float* Wmf   = (float*)carve((size_t)STEPS * 16384 * 4);
    float* Wihf  = (float*)carve(49152 * 4);
    float* Whhf  = (float*)carve(49152 * 4);
    float* bihf  = (float*)carve(384 * 4);
    float* bhhf  = (float*)carve(384 * 4);
    float* Wpf   = (float*)carve(128 * 4);
    float* bpf   = (float*)carve(4);
    float* Wcomb = (float*)carve((size_t)STEPS * 49152 * 4);
    unsigned short* Bci = (unsigned short*)carve((size_t)STEPS * 49152 * 2);
    unsigned short* Bhh = (unsigned short*)carve(49152 * 2);
    unsigned short* Bin = (unsigned short*)carve(8192 * 2);
    float* bip   = (float*)carve(384 * 4);
    float* bhp   = (float*)carve(384 * 4);
    unsigned short* hA   = (unsigned short*)carve(((size_t)N * 128 + 16384) * 2);
    unsigned short* hB   = (unsigned short*)carve(((size_t)N * 128 + 16384) * 2);
    unsigned short* aggb = (unsigned short*)carve(((size_t)N * 128 + 16384) * 2);
    int*   gcnt  = (int*)carve(256 * 4);
    int*   cbase = (int*)carve(257 * 4);
    int*   offs  = (int*)carve((size_t)(N + 1) * 4);
    int*   csr   = (int*)carve((size_t)E * 4);
    uint2* pair2 = (uint2*)carve((size_t)NCO * ccap * 8);
    float* accb  = (float*)carve(128 * 4);

    hipMemsetAsync(gcnt, 0, 256 * 4, stream);
    hipMemsetAsync(accb, 0, 128 * 4, stream);

    detect_kernel<<<1, 256, 0, stream>>>((const unsigned int*)x, ei, flags);

    {
        int total = 8192 + STEPS * 16384 + 2 * 49152 + 768 + 129;
        convall_kernel<<<(total + 255) / 256, 256, 0, stream>>>(
            W_in, W_mpnn, W_ih, W_hh, b_ih, b_hh, W_pred, b_pred,
            Winf, Wmf, Wihf, Whhf, bihf, bhhf, Wpf, bpf, STEPS, flags);
    }

    wcomb_kernel<<<(STEPS * 49152 + 255) / 256, 256, 0, stream>>>(Wmf, Wihf, Wcomb, STEPS);
    {
        int total = (STEPS + 1) * 49152 + 768;
        pack_gates<<<(total + 255) / 256, 256, 0, stream>>>(Wcomb, Whhf, bihf, bhhf,
                                                            Bci, Bhh, bip, bhp, STEPS);
    }
    pack_in<<<32, 256, 0, stream>>>(Winf, Bin);

    // h0 = x @ W_in^T (reads raw x, runtime dtype)
    gemm_in<<<(N + 31) / 32, 256, 0, stream>>>(x, flags, Bin, hA, N);

    // CSR build: radix partition -> coarse scan -> per-bucket counting sort
    part1_kernel<<<256, 256, 0, stream>>>(ei, E, flags, gcnt, pair2, NCO, cshift, ccap, chunk);
    scanco_kernel<<<1, 256, 0, stream>>>(gcnt, cbase, NCO, ccap);
    part2_kernel<<<NCO, 256, 0, stream>>>(pair2, gcnt, cbase, offs, csr, N, NCO, cshift, ccap);

    unsigned short* hcur = hA;
    unsigned short* hnxt = hB;
    for (int step = 0; step < STEPS; ++step) {
        aggregate<<<(N + 3) / 4, 256, 0, stream>>>(hcur, offs, csr, aggb, N);
        step_kernel<<<(N + 31) / 32, 512, 0, stream>>>(
            hcur, aggb, Bci + (size_t)step * 49152, Bhh, bip, bhp, hnxt, N);
        unsigned short* t = hcur; hcur = hnxt; hnxt = t;
    }

    colsum<<<512, 256, 0, stream>>>(hcur, accb, N);
    finalize<<<1, 128, 0, stream>>>(accb, Wpf, bpf, (unsigned int*)d_out, 1.f / (float)N);
}